// Round 1
// baseline (155.952 us; speedup 1.0000x reference)
//
#include <hip/hip_runtime.h>
#include <hip/hip_bf16.h>

#define NUM_TOKENS 16384
#define DIM 4096
#define NE 8
#define NSLOTS (NUM_TOKENS * 2)  // 32768

// ---------------- Kernel 1: gate GEMV + sigmoid + top-2 ----------------
// grid 256 x 1024 threads. Each block: 64 tokens (16 waves x 4 tokens/wave).
// W (8x4096 f32 = 128 KiB) staged in LDS once per block.
__global__ __launch_bounds__(1024) void router_gemv(
    const float* __restrict__ x, const float* __restrict__ W,
    int* __restrict__ experts_ws, float* __restrict__ scores_ws)
{
    __shared__ float4 Wlds[NE * (DIM / 4)];  // 8192 float4 = 128 KiB

    const int tid = threadIdx.x;
    const float4* W4 = reinterpret_cast<const float4*>(W);
#pragma unroll
    for (int k = 0; k < 8; ++k)
        Wlds[tid + k * 1024] = W4[tid + k * 1024];
    __syncthreads();

    const int wave = tid >> 6;
    const int lane = tid & 63;
    const int tok0 = blockIdx.x * 64 + wave * 4;

    const float4* x4 = reinterpret_cast<const float4*>(x);
    const float4* xr0 = x4 + (size_t)(tok0 + 0) * (DIM / 4);
    const float4* xr1 = x4 + (size_t)(tok0 + 1) * (DIM / 4);
    const float4* xr2 = x4 + (size_t)(tok0 + 2) * (DIM / 4);
    const float4* xr3 = x4 + (size_t)(tok0 + 3) * (DIM / 4);

    float acc[4][8];
#pragma unroll
    for (int t = 0; t < 4; ++t)
#pragma unroll
        for (int e = 0; e < 8; ++e) acc[t][e] = 0.f;

#pragma unroll 4
    for (int it = 0; it < 16; ++it) {
        const int f4i = it * 64 + lane;
        float4 xa = xr0[f4i];
        float4 xb = xr1[f4i];
        float4 xc = xr2[f4i];
        float4 xd = xr3[f4i];
#pragma unroll
        for (int e = 0; e < 8; ++e) {
            float4 w = Wlds[e * 1024 + f4i];
            acc[0][e] = fmaf(xa.w, w.w, fmaf(xa.z, w.z, fmaf(xa.y, w.y, fmaf(xa.x, w.x, acc[0][e]))));
            acc[1][e] = fmaf(xb.w, w.w, fmaf(xb.z, w.z, fmaf(xb.y, w.y, fmaf(xb.x, w.x, acc[1][e]))));
            acc[2][e] = fmaf(xc.w, w.w, fmaf(xc.z, w.z, fmaf(xc.y, w.y, fmaf(xc.x, w.x, acc[2][e]))));
            acc[3][e] = fmaf(xd.w, w.w, fmaf(xd.z, w.z, fmaf(xd.y, w.y, fmaf(xd.x, w.x, acc[3][e]))));
        }
    }

    // butterfly reduce each of the 32 accumulators across 64 lanes
#pragma unroll
    for (int t = 0; t < 4; ++t)
#pragma unroll
        for (int e = 0; e < 8; ++e) {
            float v = acc[t][e];
#pragma unroll
            for (int d = 1; d < 64; d <<= 1) v += __shfl_xor(v, d, 64);
            acc[t][e] = v;
        }

    if (lane < 4) {
        const int t = lane;
        float s[8];
#pragma unroll
        for (int e = 0; e < 8; ++e) s[e] = 1.0f / (1.0f + expf(-acc[t][e]));
        // top-2, ties -> lower index (matches lax.top_k)
        float v1 = -1.0f; int e1 = 0;
#pragma unroll
        for (int e = 0; e < 8; ++e)
            if (s[e] > v1) { v1 = s[e]; e1 = e; }
        float v2 = -1.0f; int e2 = 0;
#pragma unroll
        for (int e = 0; e < 8; ++e)
            if (e != e1 && s[e] > v2) { v2 = s[e]; e2 = e; }
        const int tg = tok0 + t;
        experts_ws[2 * tg + 0] = e1;
        experts_ws[2 * tg + 1] = e2;
        scores_ws[2 * tg + 0] = v1;
        scores_ws[2 * tg + 1] = v2;
    }
}

// ---------------- Kernel 2: stable counting sort by expert ----------------
// Single block, 1024 threads, 32 slots/thread. Deterministic (no atomics).
// out = [scores_sorted (32768) | token_indices as f32 (32768) | counts as f32 (8)]
__global__ __launch_bounds__(1024) void router_sort(
    const int* __restrict__ experts_ws, const float* __restrict__ scores_ws,
    float* __restrict__ out)
{
    const int tid = threadIdx.x;
    const int lane = tid & 63;
    const int wave = tid >> 6;

    __shared__ unsigned long long wsum0[16], wsum1[16];
    __shared__ unsigned int totals[NE];

    const int base = tid * 32;
    int el[32];
    const int4* e4 = reinterpret_cast<const int4*>(experts_ws + base);
#pragma unroll
    for (int i = 0; i < 8; ++i) {
        int4 v = e4[i];
        el[4 * i + 0] = v.x; el[4 * i + 1] = v.y;
        el[4 * i + 2] = v.z; el[4 * i + 3] = v.w;
    }

    // local histogram packed: h0 = experts 0..3 (16b fields), h1 = experts 4..7
    unsigned long long h0 = 0ull, h1 = 0ull;
#pragma unroll
    for (int i = 0; i < 32; ++i) {
        const int e = el[i];
        if (e < 4) h0 += 1ull << (16 * e);
        else       h1 += 1ull << (16 * (e - 4));
    }
    const unsigned long long own0 = h0, own1 = h1;

    // inclusive scan across the wave
#pragma unroll
    for (int d = 1; d < 64; d <<= 1) {
        unsigned long long n0 = __shfl_up(h0, d, 64);
        unsigned long long n1 = __shfl_up(h1, d, 64);
        if (lane >= d) { h0 += n0; h1 += n1; }
    }
    if (lane == 63) { wsum0[wave] = h0; wsum1[wave] = h1; }
    __syncthreads();

    // serial scan over the 16 wave partials (trivial), also grand totals
    if (tid == 0) {
        unsigned long long r0 = 0ull, r1 = 0ull;
        for (int j = 0; j < 16; ++j) {
            unsigned long long t0 = wsum0[j], t1 = wsum1[j];
            wsum0[j] = r0; wsum1[j] = r1;
            r0 += t0; r1 += t1;
        }
        for (int e = 0; e < 4; ++e) totals[e]     = (unsigned)((r0 >> (16 * e)) & 0xFFFFull);
        for (int e = 0; e < 4; ++e) totals[4 + e] = (unsigned)((r1 >> (16 * e)) & 0xFFFFull);
    }
    __syncthreads();

    // expert base offsets (exclusive prefix over totals)
    unsigned int run = 0, eb[NE];
#pragma unroll
    for (int e = 0; e < NE; ++e) { eb[e] = run; run += totals[e]; }

    // per-thread exclusive offsets, packed back into two u64s (absolute positions,
    // each < 32768 so 16-bit fields never overflow; avoids runtime-indexed array)
    const unsigned long long ex0 = h0 - own0 + wsum0[wave];
    const unsigned long long ex1 = h1 - own1 + wsum1[wave];
    unsigned long long po0 = 0ull, po1 = 0ull;
#pragma unroll
    for (int e = 0; e < 4; ++e) {
        po0 |= (unsigned long long)(eb[e]     + (unsigned)((ex0 >> (16 * e)) & 0xFFFFull)) << (16 * e);
        po1 |= (unsigned long long)(eb[4 + e] + (unsigned)((ex1 >> (16 * e)) & 0xFFFFull)) << (16 * e);
    }

    if (tid < NE) out[2 * NSLOTS + tid] = (float)totals[tid];

    const float* sc = scores_ws + base;
#pragma unroll
    for (int i = 0; i < 32; ++i) {
        const int e = el[i];
        unsigned int p;
        if (e < 4) {
            const int sh = 16 * e;
            p = (unsigned int)((po0 >> sh) & 0xFFFFull);
            po0 += 1ull << sh;
        } else {
            const int sh = 16 * (e - 4);
            p = (unsigned int)((po1 >> sh) & 0xFFFFull);
            po1 += 1ull << sh;
        }
        out[p] = sc[i];
        out[NSLOTS + p] = (float)((base + i) >> 1);
    }
}

extern "C" void kernel_launch(void* const* d_in, const int* in_sizes, int n_in,
                              void* d_out, int out_size, void* d_ws, size_t ws_size,
                              hipStream_t stream) {
    const float* x = (const float*)d_in[0];
    const float* W = (const float*)d_in[1];
    float* out = (float*)d_out;

    int*   experts_ws = (int*)d_ws;
    float* scores_ws  = (float*)((char*)d_ws + (size_t)NSLOTS * sizeof(int));

    router_gemv<<<NUM_TOKENS / 64, 1024, 0, stream>>>(x, W, experts_ws, scores_ws);
    router_sort<<<1, 1024, 0, stream>>>(experts_ws, scores_ws, out);
}

// Round 2
// 70.238 us; speedup vs baseline: 2.2203x; 2.2203x over previous
//
#include <hip/hip_runtime.h>
#include <hip/hip_bf16.h>

#define NUM_TOKENS 16384
#define DIM 4096
#define NE 8
#define NSLOTS (NUM_TOKENS * 2)  // 32768
#define SORT_NB 128              // sort blocks
#define SORT_BT 256              // threads per sort block (1 slot/thread)

// ---------------- Kernel 1: gate GEMV + sigmoid + top-2 ----------------
// (unchanged from round 1 — control)
__global__ __launch_bounds__(1024) void router_gemv(
    const float* __restrict__ x, const float* __restrict__ W,
    int* __restrict__ experts_ws, float* __restrict__ scores_ws)
{
    __shared__ float4 Wlds[NE * (DIM / 4)];  // 128 KiB

    const int tid = threadIdx.x;
    const float4* W4 = reinterpret_cast<const float4*>(W);
#pragma unroll
    for (int k = 0; k < 8; ++k)
        Wlds[tid + k * 1024] = W4[tid + k * 1024];
    __syncthreads();

    const int wave = tid >> 6;
    const int lane = tid & 63;
    const int tok0 = blockIdx.x * 64 + wave * 4;

    const float4* x4 = reinterpret_cast<const float4*>(x);
    const float4* xr0 = x4 + (size_t)(tok0 + 0) * (DIM / 4);
    const float4* xr1 = x4 + (size_t)(tok0 + 1) * (DIM / 4);
    const float4* xr2 = x4 + (size_t)(tok0 + 2) * (DIM / 4);
    const float4* xr3 = x4 + (size_t)(tok0 + 3) * (DIM / 4);

    float acc[4][8];
#pragma unroll
    for (int t = 0; t < 4; ++t)
#pragma unroll
        for (int e = 0; e < 8; ++e) acc[t][e] = 0.f;

#pragma unroll 4
    for (int it = 0; it < 16; ++it) {
        const int f4i = it * 64 + lane;
        float4 xa = xr0[f4i];
        float4 xb = xr1[f4i];
        float4 xc = xr2[f4i];
        float4 xd = xr3[f4i];
#pragma unroll
        for (int e = 0; e < 8; ++e) {
            float4 w = Wlds[e * 1024 + f4i];
            acc[0][e] = fmaf(xa.w, w.w, fmaf(xa.z, w.z, fmaf(xa.y, w.y, fmaf(xa.x, w.x, acc[0][e]))));
            acc[1][e] = fmaf(xb.w, w.w, fmaf(xb.z, w.z, fmaf(xb.y, w.y, fmaf(xb.x, w.x, acc[1][e]))));
            acc[2][e] = fmaf(xc.w, w.w, fmaf(xc.z, w.z, fmaf(xc.y, w.y, fmaf(xc.x, w.x, acc[2][e]))));
            acc[3][e] = fmaf(xd.w, w.w, fmaf(xd.z, w.z, fmaf(xd.y, w.y, fmaf(xd.x, w.x, acc[3][e]))));
        }
    }

#pragma unroll
    for (int t = 0; t < 4; ++t)
#pragma unroll
        for (int e = 0; e < 8; ++e) {
            float v = acc[t][e];
#pragma unroll
            for (int d = 1; d < 64; d <<= 1) v += __shfl_xor(v, d, 64);
            acc[t][e] = v;
        }

    if (lane < 4) {
        const int t = lane;
        float s[8];
#pragma unroll
        for (int e = 0; e < 8; ++e) s[e] = 1.0f / (1.0f + expf(-acc[t][e]));
        float v1 = -1.0f; int e1 = 0;
#pragma unroll
        for (int e = 0; e < 8; ++e)
            if (s[e] > v1) { v1 = s[e]; e1 = e; }
        float v2 = -1.0f; int e2 = 0;
#pragma unroll
        for (int e = 0; e < 8; ++e)
            if (e != e1 && s[e] > v2) { v2 = s[e]; e2 = e; }
        const int tg = tok0 + t;
        experts_ws[2 * tg + 0] = e1;
        experts_ws[2 * tg + 1] = e2;
        scores_ws[2 * tg + 0] = v1;
        scores_ws[2 * tg + 1] = v2;
    }
}

// ---------------- Sort phase A: per-slot local rank + per-block histogram ----
// 128 blocks x 256 threads, 1 slot/thread. Packed u64 one-hot scan
// (8 experts -> 2 x u64 of 16-bit fields; max field value 256 fits).
__global__ __launch_bounds__(SORT_BT) void sort_rank(
    const int* __restrict__ experts_ws,
    unsigned short* __restrict__ ranks_ws,
    unsigned long long* __restrict__ blockhist_ws)  // [SORT_NB][2]
{
    __shared__ unsigned long long wsum0[4], wsum1[4];

    const int tid = threadIdx.x;
    const int lane = tid & 63;
    const int wave = tid >> 6;
    const int s = blockIdx.x * SORT_BT + tid;

    const int e = experts_ws[s];  // coalesced

    unsigned long long h0 = 0ull, h1 = 0ull;
    if (e < 4) h0 = 1ull << (16 * e);
    else       h1 = 1ull << (16 * (e - 4));
    const unsigned long long own0 = h0, own1 = h1;

#pragma unroll
    for (int d = 1; d < 64; d <<= 1) {
        unsigned long long n0 = __shfl_up(h0, d, 64);
        unsigned long long n1 = __shfl_up(h1, d, 64);
        if (lane >= d) { h0 += n0; h1 += n1; }
    }
    if (lane == 63) { wsum0[wave] = h0; wsum1[wave] = h1; }
    __syncthreads();

    if (tid == 0) {
        unsigned long long r0 = 0ull, r1 = 0ull;
        for (int j = 0; j < 4; ++j) {
            unsigned long long t0 = wsum0[j], t1 = wsum1[j];
            wsum0[j] = r0; wsum1[j] = r1;
            r0 += t0; r1 += t1;
        }
        // r0,r1 now block totals
        blockhist_ws[2 * blockIdx.x + 0] = r0;
        blockhist_ws[2 * blockIdx.x + 1] = r1;
    }
    __syncthreads();

    const unsigned long long ex0 = h0 - own0 + wsum0[wave];
    const unsigned long long ex1 = h1 - own1 + wsum1[wave];
    unsigned int rank;
    if (e < 4) rank = (unsigned int)((ex0 >> (16 * e)) & 0xFFFFull);
    else       rank = (unsigned int)((ex1 >> (16 * (e - 4))) & 0xFFFFull);
    ranks_ws[s] = (unsigned short)rank;  // coalesced u16
}

// ---------------- Sort phase B: scan block histograms -> packed offsets ------
// 1 block x 128 threads (2 waves), thread b owns block b's histogram pair.
__global__ __launch_bounds__(128) void sort_offsets(
    const unsigned long long* __restrict__ blockhist_ws,
    unsigned long long* __restrict__ offs_ws,  // [SORT_NB][2]
    float* __restrict__ out)
{
    __shared__ unsigned long long wt0[2], wt1[2];

    const int t = threadIdx.x;
    const int lane = t & 63;
    const int wave = t >> 6;

    unsigned long long h0 = blockhist_ws[2 * t + 0];
    unsigned long long h1 = blockhist_ws[2 * t + 1];
    const unsigned long long own0 = h0, own1 = h1;

#pragma unroll
    for (int d = 1; d < 64; d <<= 1) {
        unsigned long long n0 = __shfl_up(h0, d, 64);
        unsigned long long n1 = __shfl_up(h1, d, 64);
        if (lane >= d) { h0 += n0; h1 += n1; }
    }
    if (lane == 63) { wt0[wave] = h0; wt1[wave] = h1; }
    __syncthreads();

    const unsigned long long wb0 = (wave == 1) ? wt0[0] : 0ull;
    const unsigned long long wb1 = (wave == 1) ? wt1[0] : 0ull;
    const unsigned long long gt0 = wt0[0] + wt0[1];  // grand totals packed
    const unsigned long long gt1 = wt1[0] + wt1[1];

    // expert totals and exclusive bases
    unsigned int tot[NE];
#pragma unroll
    for (int e = 0; e < 4; ++e) tot[e]     = (unsigned)((gt0 >> (16 * e)) & 0xFFFFull);
#pragma unroll
    for (int e = 0; e < 4; ++e) tot[4 + e] = (unsigned)((gt1 >> (16 * e)) & 0xFFFFull);
    unsigned int run = 0, eb[NE];
#pragma unroll
    for (int e = 0; e < NE; ++e) { eb[e] = run; run += tot[e]; }
    unsigned long long pb0 = 0ull, pb1 = 0ull;
#pragma unroll
    for (int e = 0; e < 4; ++e) {
        pb0 |= (unsigned long long)eb[e]     << (16 * e);
        pb1 |= (unsigned long long)eb[4 + e] << (16 * e);
    }

    // exclusive-over-blocks + expert base; fields never exceed 32768 -> no carry
    const unsigned long long o0 = (h0 - own0 + wb0) + pb0;
    const unsigned long long o1 = (h1 - own1 + wb1) + pb1;
    offs_ws[2 * t + 0] = o0;
    offs_ws[2 * t + 1] = o1;

    if (t < NE) out[2 * NSLOTS + t] = (float)tot[t];
}

// ---------------- Sort phase C: scatter ----------------
__global__ __launch_bounds__(SORT_BT) void sort_scatter(
    const int* __restrict__ experts_ws, const float* __restrict__ scores_ws,
    const unsigned short* __restrict__ ranks_ws,
    const unsigned long long* __restrict__ offs_ws,
    float* __restrict__ out)
{
    const int tid = threadIdx.x;
    const int b = blockIdx.x;
    const int s = b * SORT_BT + tid;

    const int e = experts_ws[s];
    const float sc = scores_ws[s];
    const unsigned int rank = ranks_ws[s];
    const unsigned long long o0 = offs_ws[2 * b + 0];
    const unsigned long long o1 = offs_ws[2 * b + 1];

    unsigned int base;
    if (e < 4) base = (unsigned int)((o0 >> (16 * e)) & 0xFFFFull);
    else       base = (unsigned int)((o1 >> (16 * (e - 4))) & 0xFFFFull);
    const unsigned int p = base + rank;

    out[p] = sc;
    out[NSLOTS + p] = (float)(s >> 1);
}

extern "C" void kernel_launch(void* const* d_in, const int* in_sizes, int n_in,
                              void* d_out, int out_size, void* d_ws, size_t ws_size,
                              hipStream_t stream) {
    const float* x = (const float*)d_in[0];
    const float* W = (const float*)d_in[1];
    float* out = (float*)d_out;

    char* ws = (char*)d_ws;
    int*            experts_ws  = (int*)(ws);                        // 128 KiB
    float*          scores_ws   = (float*)(ws + (1 << 17));          // 128 KiB
    unsigned short* ranks_ws    = (unsigned short*)(ws + (1 << 18)); // 64 KiB
    unsigned long long* bh_ws   = (unsigned long long*)(ws + (5 << 16)); // 2 KiB
    unsigned long long* offs_ws = (unsigned long long*)(ws + (5 << 16) + 4096);

    router_gemv<<<NUM_TOKENS / 64, 1024, 0, stream>>>(x, W, experts_ws, scores_ws);
    sort_rank<<<SORT_NB, SORT_BT, 0, stream>>>(experts_ws, ranks_ws, bh_ws);
    sort_offsets<<<1, 128, 0, stream>>>(bh_ws, offs_ws, out);
    sort_scatter<<<SORT_NB, SORT_BT, 0, stream>>>(experts_ws, scores_ws, ranks_ws, offs_ws, out);
}

// Round 3
// 55.266 us; speedup vs baseline: 2.8218x; 1.2709x over previous
//
#include <hip/hip_runtime.h>
#include <hip/hip_bf16.h>

#define NUM_TOKENS 16384
#define DIM 4096
#define NE 8
#define NSLOTS (NUM_TOKENS * 2)   // 32768
#define NB1 256                   // gemv blocks (64 tokens / 128 slots each)
#define NB2 128                   // scatter blocks (256 slots each)

typedef unsigned long long u64;

__device__ __forceinline__ void onehot_add(u64& h0, u64& h1, int e) {
    if (e < 4) h0 += 1ull << (16 * e);
    else       h1 += 1ull << (16 * (e - 4));
}
__device__ __forceinline__ unsigned field_of(u64 h0, u64 h1, int e) {
    return (unsigned)(((e < 4) ? (h0 >> (16 * e)) : (h1 >> (16 * (e - 4)))) & 0xFFFFull);
}

// ---------------- Kernel 1: gemv + sigmoid + top2 + per-block rank/hist ------
__global__ __launch_bounds__(1024) void router_fused(
    const float* __restrict__ x, const float* __restrict__ W,
    float* __restrict__ scores_ws,   // [NSLOTS]
    u64* __restrict__ pr_ws,         // [NSLOTS/2] two packed u32 (rank | e<<16)
    u64* __restrict__ bh_ws)         // [NB1][2] packed block histograms
{
    __shared__ float4 Wlds[NE * (DIM / 4)];  // 128 KiB
    __shared__ int eLds[128];                // expert id per local slot

    const int tid = threadIdx.x;
    const int lane = tid & 63;
    const int wave = tid >> 6;
    const int tok0 = blockIdx.x * 64 + wave * 4;

    const float4* x4 = reinterpret_cast<const float4*>(x);
    const float4* xr0 = x4 + (size_t)(tok0 + 0) * (DIM / 4);
    const float4* xr1 = x4 + (size_t)(tok0 + 1) * (DIM / 4);
    const float4* xr2 = x4 + (size_t)(tok0 + 2) * (DIM / 4);
    const float4* xr3 = x4 + (size_t)(tok0 + 3) * (DIM / 4);

    // prefetch iteration-0 x before the staging barrier
    float4 p0 = xr0[lane];
    float4 p1 = xr1[lane];
    float4 p2 = xr2[lane];
    float4 p3 = xr3[lane];

    const float4* W4 = reinterpret_cast<const float4*>(W);
#pragma unroll
    for (int k = 0; k < 8; ++k)
        Wlds[tid + k * 1024] = W4[tid + k * 1024];
    __syncthreads();

    float a[32];
#pragma unroll
    for (int v = 0; v < 32; ++v) a[v] = 0.f;

#define GEMV_STEP(XA, XB, XC, XD, F4I)                                          \
    do {                                                                        \
        _Pragma("unroll")                                                       \
        for (int e = 0; e < 8; ++e) {                                           \
            float4 w = Wlds[e * 1024 + (F4I)];                                  \
            a[0*8+e] = fmaf((XA).w, w.w, fmaf((XA).z, w.z, fmaf((XA).y, w.y, fmaf((XA).x, w.x, a[0*8+e])))); \
            a[1*8+e] = fmaf((XB).w, w.w, fmaf((XB).z, w.z, fmaf((XB).y, w.y, fmaf((XB).x, w.x, a[1*8+e])))); \
            a[2*8+e] = fmaf((XC).w, w.w, fmaf((XC).z, w.z, fmaf((XC).y, w.y, fmaf((XC).x, w.x, a[2*8+e])))); \
            a[3*8+e] = fmaf((XD).w, w.w, fmaf((XD).z, w.z, fmaf((XD).y, w.y, fmaf((XD).x, w.x, a[3*8+e])))); \
        }                                                                       \
    } while (0)

    GEMV_STEP(p0, p1, p2, p3, lane);
#pragma unroll 3
    for (int it = 1; it < 16; ++it) {
        const int f4i = it * 64 + lane;
        float4 xa = xr0[f4i];
        float4 xb = xr1[f4i];
        float4 xc = xr2[f4i];
        float4 xd = xr3[f4i];
        GEMV_STEP(xa, xb, xc, xd, f4i);
    }

    // ---- merged butterfly: 32 values over 64 lanes, bit-identical add tree ----
    // after level m, reg i holds partial of value (i<<m) | (lane & ((1<<m)-1))
#define MERGE(DST, A, B, BIT, DIST)                       \
    do {                                                  \
        const bool sel = (lane >> (BIT)) & 1;             \
        float _lo = sel ? (B) : (A);                      \
        float _hi = sel ? (A) : (B);                      \
        DST = _lo + __shfl_xor(_hi, (DIST), 64);          \
    } while (0)

    float m1[16], m2[8], m3[4], m4[2], m5;
#pragma unroll
    for (int i = 0; i < 16; ++i) MERGE(m1[i], a[2*i], a[2*i+1], 0, 1);
#pragma unroll
    for (int i = 0; i < 8; ++i)  MERGE(m2[i], m1[2*i], m1[2*i+1], 1, 2);
#pragma unroll
    for (int i = 0; i < 4; ++i)  MERGE(m3[i], m2[2*i], m2[2*i+1], 2, 4);
#pragma unroll
    for (int i = 0; i < 2; ++i)  MERGE(m4[i], m3[2*i], m3[2*i+1], 3, 8);
    MERGE(m5, m4[0], m4[1], 4, 16);
    m5 += __shfl_xor(m5, 32, 64);
    // lane L holds full sum of value v = L&31 : t = (L>>3)&3, e = L&7

    const float s = 1.0f / (1.0f + expf(-m5));

    // ---- top-2 tournament within each 8-lane group (ties -> lower index) ----
    float v1 = s; int e1 = lane & 7;
#pragma unroll
    for (int d = 1; d < 8; d <<= 1) {
        float ov = __shfl_xor(v1, d, 64);
        int   oe = __shfl_xor(e1, d, 64);
        const bool take = (ov > v1) || (ov == v1 && oe < e1);
        v1 = take ? ov : v1;
        e1 = take ? oe : e1;
    }
    float v2 = ((lane & 7) == e1) ? -1e30f : s; int e2 = lane & 7;
#pragma unroll
    for (int d = 1; d < 8; d <<= 1) {
        float ov = __shfl_xor(v2, d, 64);
        int   oe = __shfl_xor(e2, d, 64);
        const bool take = (ov > v2) || (ov == v2 && oe < e2);
        v2 = take ? ov : v2;
        e2 = take ? oe : e2;
    }

    if ((lane & 7) == 0 && lane < 32) {
        const int t = lane >> 3;
        const int tok = tok0 + t;
        reinterpret_cast<float2*>(scores_ws)[tok] = make_float2(v1, v2);
        reinterpret_cast<int2*>(eLds)[wave * 4 + t] = make_int2(e1, e2);
    }
    __syncthreads();

    // ---- wave 0: stable rank scan over this block's 128 slots ----
    if (wave == 0) {
        const int2 ee = reinterpret_cast<const int2*>(eLds)[lane];  // slots 2L, 2L+1
        u64 h0 = 0ull, h1 = 0ull;
        onehot_add(h0, h1, ee.x);
        onehot_add(h0, h1, ee.y);
        const u64 own0 = h0, own1 = h1;
#pragma unroll
        for (int d = 1; d < 64; d <<= 1) {
            u64 n0 = __shfl_up(h0, d, 64);
            u64 n1 = __shfl_up(h1, d, 64);
            if (lane >= d) { h0 += n0; h1 += n1; }
        }
        u64 ex0 = h0 - own0, ex1 = h1 - own1;
        const unsigned rankA = field_of(ex0, ex1, ee.x);
        onehot_add(ex0, ex1, ee.x);
        const unsigned rankB = field_of(ex0, ex1, ee.y);
        const u64 packed = (u64)(rankA | ((unsigned)ee.x << 16)) |
                           ((u64)(rankB | ((unsigned)ee.y << 16)) << 32);
        pr_ws[blockIdx.x * 64 + lane] = packed;

        const u64 t0 = __shfl(h0, 63, 64);
        const u64 t1 = __shfl(h1, 63, 64);
        if (lane == 0) {
            bh_ws[2 * blockIdx.x + 0] = t0;
            bh_ws[2 * blockIdx.x + 1] = t1;
        }
    }
}

// ---------------- Kernel 2: global offsets (redundant scan) + scatter --------
__global__ __launch_bounds__(256) void router_scatter(
    const float* __restrict__ scores_ws,
    const u64* __restrict__ pr_ws,
    const u64* __restrict__ bh_ws,
    float* __restrict__ out)
{
    __shared__ u64 offsLds[4];   // (o0,o1) for entry 2b and 2b+1
    __shared__ float totLds[NE];

    const int tid = threadIdx.x;
    const int lane = tid & 63;
    const int wave = tid >> 6;
    const int b = blockIdx.x;

    if (wave == 0) {
        // lane L owns histogram entries 4L..4L+3
        const ulonglong2* bh2 = reinterpret_cast<const ulonglong2*>(bh_ws);
        const ulonglong2 hA = bh2[4 * lane + 0];
        const ulonglong2 hB = bh2[4 * lane + 1];
        const ulonglong2 hC = bh2[4 * lane + 2];
        const ulonglong2 hD = bh2[4 * lane + 3];

        const u64 ex1_0 = hA.x,         ex1_1 = hA.y;
        const u64 ex2_0 = ex1_0 + hB.x, ex2_1 = ex1_1 + hB.y;
        const u64 ex3_0 = ex2_0 + hC.x, ex3_1 = ex2_1 + hC.y;
        const u64 inc0  = ex3_0 + hD.x, inc1  = ex3_1 + hD.y;

        u64 s0 = inc0, s1 = inc1;
#pragma unroll
        for (int d = 1; d < 64; d <<= 1) {
            u64 n0 = __shfl_up(s0, d, 64);
            u64 n1 = __shfl_up(s1, d, 64);
            if (lane >= d) { s0 += n0; s1 += n1; }
        }
        const u64 base0 = s0 - inc0, base1 = s1 - inc1;  // exclusive lane base
        const u64 g0 = __shfl(s0, 63, 64);               // grand totals packed
        const u64 g1 = __shfl(s1, 63, 64);

        // expert exclusive bases packed
        unsigned t0e = (unsigned)((g0 >>  0) & 0xFFFF), t1e = (unsigned)((g0 >> 16) & 0xFFFF);
        unsigned t2e = (unsigned)((g0 >> 32) & 0xFFFF), t3e = (unsigned)((g0 >> 48) & 0xFFFF);
        unsigned t4e = (unsigned)((g1 >>  0) & 0xFFFF), t5e = (unsigned)((g1 >> 16) & 0xFFFF);
        unsigned t6e = (unsigned)((g1 >> 32) & 0xFFFF);
        unsigned b0 = 0, b1 = b0 + t0e, b2 = b1 + t1e, b3 = b2 + t2e;
        unsigned b4 = b3 + t3e, b5 = b4 + t4e, b6 = b5 + t5e, b7 = b6 + t6e;
        const u64 pb0 = (u64)b0 | ((u64)b1 << 16) | ((u64)b2 << 32) | ((u64)b3 << 48);
        const u64 pb1 = (u64)b4 | ((u64)b5 << 16) | ((u64)b6 << 32) | ((u64)b7 << 48);

        if (lane == (b >> 1)) {
            u64 x0_0, x0_1, x1_0, x1_1;
            if (b & 1) { x0_0 = ex2_0; x0_1 = ex2_1; x1_0 = ex3_0; x1_1 = ex3_1; }
            else       { x0_0 = 0ull;  x0_1 = 0ull;  x1_0 = ex1_0; x1_1 = ex1_1; }
            offsLds[0] = base0 + x0_0 + pb0;
            offsLds[1] = base1 + x0_1 + pb1;
            offsLds[2] = base0 + x1_0 + pb0;
            offsLds[3] = base1 + x1_1 + pb1;
        }
        if (lane < NE) {
            const unsigned tv = (unsigned)((((lane < 4) ? (g0 >> (16 * lane))
                                                        : (g1 >> (16 * (lane - 4)))) & 0xFFFFull));
            totLds[lane] = (float)tv;
        }
    }
    __syncthreads();

    if (b == 0 && tid < NE) out[2 * NSLOTS + tid] = totLds[tid];

    const int s = b * 256 + tid;
    const unsigned pr = reinterpret_cast<const unsigned*>(pr_ws)[s];
    const unsigned rank = pr & 0xFFFFu;
    const int e = (int)(pr >> 16);
    const int half = tid >> 7;
    const u64 o0 = offsLds[2 * half + 0];
    const u64 o1 = offsLds[2 * half + 1];
    const unsigned p = field_of(o0, o1, e) + rank;

    out[p] = scores_ws[s];
    out[NSLOTS + p] = (float)(s >> 1);
}

extern "C" void kernel_launch(void* const* d_in, const int* in_sizes, int n_in,
                              void* d_out, int out_size, void* d_ws, size_t ws_size,
                              hipStream_t stream) {
    const float* x = (const float*)d_in[0];
    const float* W = (const float*)d_in[1];
    float* out = (float*)d_out;

    char* ws = (char*)d_ws;
    float* scores_ws = (float*)(ws);                 // 128 KiB
    u64*   pr_ws     = (u64*)(ws + (1 << 17));       // 128 KiB
    u64*   bh_ws     = (u64*)(ws + (1 << 18));       // 4 KiB

    router_fused<<<NB1, 1024, 0, stream>>>(x, W, scores_ws, pr_ws, bh_ws);
    router_scatter<<<NB2, 256, 0, stream>>>(scores_ws, pr_ws, bh_ws, out);
}